// Round 8
// baseline (286.336 us; speedup 1.0000x reference)
//
#include <hip/hip_runtime.h>
#include <hip/hip_bf16.h>
#include <stdint.h>

// CirculantLinear == dense GEMM: y[b,o] = sum_n x[b,n]*rows[o,n] + bias[o]
// where rows[o,n] = c[o, (4096-n) & 4095].
// M=8192, N=4096, K=4096. fp32 in/out, bf16 MFMA inside.
// R3: swizzle fix -> conflicts 0 (248us). R4: 32x32 regressed. R5/R7: schedule
// variants null (242-246us, ~55% MFMA-pipe util).
// R8: FAITHFUL m201-template port: 2-barrier phases with lgkmcnt(0) (doubles
//     as WAR cert), vmcnt(6) ONLY at ph4/ph8 (3 half-tiles always in flight),
//     7-half-tile prologue, reads 12/4/8/0 per K-tile, stage trails reads.

#define B_DIM  8192
#define OUT_DIM 4096
#define IN_DIM  4096

typedef __attribute__((ext_vector_type(8))) short bf16x8;
typedef __attribute__((ext_vector_type(4))) float f32x4;
typedef __attribute__((ext_vector_type(8))) unsigned short u16x8;

__device__ __forceinline__ unsigned short f2bf(float f) {
  unsigned u = __float_as_uint(f);
  return (unsigned short)((u + 0x7fffu + ((u >> 16) & 1u)) >> 16);
}

// ---- fused conversion kernel --------------------------------------------

#define XCHUNKS (B_DIM * IN_DIM / 8 / 256)
#define RCHUNKS (OUT_DIM * IN_DIM / 8 / 256)

__global__ void cvt_fused_kernel(const float* __restrict__ x,
                                 const float* __restrict__ c,
                                 unsigned short* __restrict__ xb,
                                 unsigned short* __restrict__ rb) {
  int b = blockIdx.x;
  if (b < XCHUNKS) {
    size_t i = ((size_t)b * 256 + threadIdx.x) * 8;
    const float4* p = (const float4*)(x + i);
    float4 a = p[0];
    float4 q = p[1];
    u16x8 o;
    o[0] = f2bf(a.x); o[1] = f2bf(a.y); o[2] = f2bf(a.z); o[3] = f2bf(a.w);
    o[4] = f2bf(q.x); o[5] = f2bf(q.y); o[6] = f2bf(q.z); o[7] = f2bf(q.w);
    *(u16x8*)(xb + i) = o;
  } else {
    int idx = (b - XCHUNKS) * 256 + threadIdx.x;
    int o  = idx >> 9;
    int n0 = (idx & 511) << 3;
    const float* crow = c + (size_t)o * IN_DIM;
    u16x8 v;
#pragma unroll
    for (int j = 0; j < 8; ++j) {
      int n = n0 + j;
      int s = (IN_DIM - n) & (IN_DIM - 1);
      v[j] = f2bf(crow[s]);
    }
    *(u16x8*)(rb + (size_t)o * IN_DIM + n0) = v;
  }
}

// ---- GEMM ---------------------------------------------------------------

__device__ __forceinline__ void async_copy16(const void* g, void* l) {
  __builtin_amdgcn_global_load_lds(
      (const __attribute__((address_space(1))) void*)g,
      (__attribute__((address_space(3))) void*)l, 16, 0, 0);
}

#define SMEM_BUF 65536
// Slots (16KB each): base(BUF,MAT,KK) = BUF*64K + MAT*32K + KK*16K.
// khalf = row-major [256][32] bf16, 64B rows, chunk-XOR swizzle
// phys_chunk = logical ^ ((row>>1)&3) (measured 0 conflicts); stage side
// applies the inverse via the per-lane GLOBAL address (LDS dest linear).

#define STAGE(BUF, MAT, KK, srcp)                                            \
  async_copy16((srcp), smem + (BUF)*SMEM_BUF + (MAT)*32768 + (KK)*16384 +    \
                           w * 1024);                                        \
  async_copy16((srcp) + 128 * IN_DIM,                                       \
               smem + (BUF)*SMEM_BUF + (MAT)*32768 + (KK)*16384 + 8192 +    \
                   w * 1024)

#define LDSA(BUF, KK, i)                                                     \
  (*(const bf16x8*)(smem + (BUF)*SMEM_BUF + (KK)*16384 + aRd + (i) * 1024))
#define LDSB(BUF, KK, i)                                                     \
  (*(const bf16x8*)(smem + (BUF)*SMEM_BUF + 32768 + (KK)*16384 + bRd +      \
                    (i) * 1024))

#define READA8(BUF, KK)                                                      \
  aR0 = LDSA(BUF, KK, 0); aR1 = LDSA(BUF, KK, 1);                            \
  aR2 = LDSA(BUF, KK, 2); aR3 = LDSA(BUF, KK, 3);                            \
  aR4 = LDSA(BUF, KK, 4); aR5 = LDSA(BUF, KK, 5);                            \
  aR6 = LDSA(BUF, KK, 6); aR7 = LDSA(BUF, KK, 7)
#define READB4(d, BUF, KK)                                                   \
  d##0 = LDSB(BUF, KK, 0); d##1 = LDSB(BUF, KK, 1);                          \
  d##2 = LDSB(BUF, KK, 2); d##3 = LDSB(BUF, KK, 3)

#define MM(a, b, r, cc)                                                      \
  acc[r][cc] = __builtin_amdgcn_mfma_f32_16x16x32_bf16(a, b, acc[r][cc], 0, 0, 0)

#define MFMAQ(A0, A1, A2, A3, b, MH)                                         \
  __builtin_amdgcn_s_setprio(1);                                             \
  MM(A0, b##0, (MH)*4+0, 0); MM(A0, b##1, (MH)*4+0, 1);                      \
  MM(A0, b##2, (MH)*4+0, 2); MM(A0, b##3, (MH)*4+0, 3);                      \
  MM(A1, b##0, (MH)*4+1, 0); MM(A1, b##1, (MH)*4+1, 1);                      \
  MM(A1, b##2, (MH)*4+1, 2); MM(A1, b##3, (MH)*4+1, 3);                      \
  MM(A2, b##0, (MH)*4+2, 0); MM(A2, b##1, (MH)*4+2, 1);                      \
  MM(A2, b##2, (MH)*4+2, 2); MM(A2, b##3, (MH)*4+2, 3);                      \
  MM(A3, b##0, (MH)*4+3, 0); MM(A3, b##1, (MH)*4+3, 1);                      \
  MM(A3, b##2, (MH)*4+3, 2); MM(A3, b##3, (MH)*4+3, 3);                      \
  __builtin_amdgcn_s_setprio(0)

#define LGKM0  asm volatile("s_waitcnt lgkmcnt(0)" ::: "memory")
#define LGKM8  asm volatile("s_waitcnt lgkmcnt(8)" ::: "memory")
#define VMC6   asm volatile("s_waitcnt vmcnt(6)" ::: "memory")
#define VMC0   asm volatile("s_waitcnt vmcnt(0)" ::: "memory")
#define BAR    __builtin_amdgcn_s_barrier()

__global__ __launch_bounds__(512, 2) void gemm_kernel(
    const unsigned short* __restrict__ xb,   // [8192][4096] bf16
    const unsigned short* __restrict__ rb,   // [4096][4096] bf16 (rows)
    const float* __restrict__ bias,          // [4096]
    float* __restrict__ out) {               // [8192][4096] fp32
  __shared__ __align__(16) char smem[2 * SMEM_BUF];  // 128 KiB

  const int tid = threadIdx.x;
  const int w = tid >> 6, l = tid & 63;
  const int wr = w >> 2, wc = w & 3;       // 2 x 4 wave grid, wave owns 128x64

  // bijective XCD swizzle: 512 blocks = 8 XCDs x 64
  const int orig = blockIdx.x;
  const int wg = (orig & 7) * 64 + (orig >> 3);
  const int bm = (wg >> 4) * 256;
  const int bn = (wg & 15) * 256;

  // staging addresses (pre-swizzled global col, LDS dest linear)
  const int sgr = w * 16 + (l >> 2);
  const int sgc = ((l & 3) ^ ((l >> 3) & 3)) << 3;
  const unsigned short* sA = xb + (size_t)(bm + sgr) * IN_DIM + sgc;
  const unsigned short* sB = rb + (size_t)(bn + sgr) * IN_DIM + sgc;

  // frag reads: phys chunk = (l>>4) ^ ((l>>1)&3)
  const int swz = ((l >> 4) ^ ((l >> 1) & 3)) << 4;
  const int aRd = (wr * 128 + (l & 15)) * 64 + swz;
  const int bRd = (wc * 64 + (l & 15)) * 64 + swz;

  f32x4 acc[8][4];
#pragma unroll
  for (int i = 0; i < 8; ++i)
#pragma unroll
    for (int j = 0; j < 4; ++j) acc[i][j] = (f32x4){0.f, 0.f, 0.f, 0.f};

  bf16x8 aR0, aR1, aR2, aR3, aR4, aR5, aR6, aR7;
  bf16x8 bP0, bP1, bP2, bP3, bQ0, bQ1, bQ2, bQ3;

  // ---- prologue: stage s1,s2,s4,s3,s5,s6,s8 (7 half-tiles, FIFO order)
  STAGE(0, 0, 0, sA);        // s1: A0.kh0
  STAGE(0, 1, 0, sB);        // s2: B0.kh0
  STAGE(0, 1, 1, sB + 32);   // s4: B0.kh1
  STAGE(0, 0, 1, sA + 32);   // s3: A0.kh1
  STAGE(1, 0, 0, sA + 64);   // s5: A1.kh0
  STAGE(1, 1, 0, sB + 64);   // s6: B1.kh0
  STAGE(1, 1, 1, sB + 96);   // s8: B1.kh1
  VMC6;                      // completes s1,s2,s4,s3; [s5,s6,s8] in flight
  BAR;

  // ---- main loop: 31 pairs (kt 0..61); pair p at sA (advanced 128/pair)
  for (int it = 0; it < 31; ++it) {
    // ph1: read A0.kh0(8) + B0.kh0(4); stage s7 (cur b1.A.kh1)
    READA8(0, 0); READB4(bP, 0, 0);
    STAGE(1, 0, 1, sA + 96);
    LGKM8; BAR; LGKM0;
    MFMAQ(aR0, aR1, aR2, aR3, bP, 0);
    BAR;
    // ph2: read B0.kh1(4); stage s1' (next A0.kh0)
    READB4(bQ, 0, 1);
    STAGE(0, 0, 0, sA + 128);
    BAR; LGKM0;
    MFMAQ(aR4, aR5, aR6, aR7, bP, 1);
    BAR;
    // ph3: read A0.kh1(8); stage s2' (next B0.kh0)
    READA8(0, 1);
    STAGE(0, 1, 0, sB + 128);
    BAR; LGKM0;
    MFMAQ(aR0, aR1, aR2, aR3, bQ, 0);
    BAR;
    // ph4: stage s4' (next B0.kh1); vmcnt(6)
    STAGE(0, 1, 1, sB + 160);
    BAR; LGKM0;
    MFMAQ(aR4, aR5, aR6, aR7, bQ, 1);
    VMC6; BAR;
    // ph5: read A1.kh0(8) + B1.kh0(4); stage s3' (next A0.kh1)
    READA8(1, 0); READB4(bP, 1, 0);
    STAGE(0, 0, 1, sA + 160);
    LGKM8; BAR; LGKM0;
    MFMAQ(aR0, aR1, aR2, aR3, bP, 0);
    BAR;
    // ph6: read B1.kh1(4); stage s5' (next A1.kh0)
    READB4(bQ, 1, 1);
    STAGE(1, 0, 0, sA + 192);
    BAR; LGKM0;
    MFMAQ(aR4, aR5, aR6, aR7, bP, 1);
    BAR;
    // ph7: read A1.kh1(8); stage s6' (next B1.kh0)
    READA8(1, 1);
    STAGE(1, 1, 0, sB + 192);
    BAR; LGKM0;
    MFMAQ(aR0, aR1, aR2, aR3, bQ, 0);
    BAR;
    // ph8: stage s8' (next B1.kh1); vmcnt(6)
    STAGE(1, 1, 1, sB + 224);
    BAR; LGKM0;
    MFMAQ(aR4, aR5, aR6, aR7, bQ, 1);
    VMC6; BAR;
    sA += 128; sB += 128;
  }

  // ---- last pair (kt 62,63): only s7 staged; vmcnt(0) at ph4
  READA8(0, 0); READB4(bP, 0, 0);
  STAGE(1, 0, 1, sA + 96);
  LGKM8; BAR; LGKM0;
  MFMAQ(aR0, aR1, aR2, aR3, bP, 0);
  BAR;
  READB4(bQ, 0, 1);
  BAR; LGKM0;
  MFMAQ(aR4, aR5, aR6, aR7, bP, 1);
  BAR;
  READA8(0, 1);
  BAR; LGKM0;
  MFMAQ(aR0, aR1, aR2, aR3, bQ, 0);
  BAR;
  BAR; LGKM0;
  MFMAQ(aR4, aR5, aR6, aR7, bQ, 1);
  VMC0; BAR;
  READA8(1, 0); READB4(bP, 1, 0);
  BAR; LGKM0;
  MFMAQ(aR0, aR1, aR2, aR3, bP, 0);
  BAR;
  READB4(bQ, 1, 1);
  BAR; LGKM0;
  MFMAQ(aR4, aR5, aR6, aR7, bP, 1);
  BAR;
  READA8(1, 1);
  BAR; LGKM0;
  MFMAQ(aR0, aR1, aR2, aR3, bQ, 0);
  BAR;
  LGKM0;
  MFMAQ(aR4, aR5, aR6, aR7, bQ, 1);

  // ---- epilogue: C/D layout col=lane&15, row=(lane>>4)*4+reg (m89-verified)
#pragma unroll
  for (int mi = 0; mi < 8; ++mi) {
    const int row = bm + wr * 128 + mi * 16 + (l >> 4) * 4;
#pragma unroll
    for (int ni = 0; ni < 4; ++ni) {
      const int col = bn + wc * 64 + ni * 16 + (l & 15);
      const float bv = bias[col];
      float* po = out + (size_t)row * OUT_DIM + col;
#pragma unroll
      for (int r2 = 0; r2 < 4; ++r2)
        po[(size_t)r2 * OUT_DIM] = acc[mi][ni][r2] + bv;
    }
  }
}

// ---- host ---------------------------------------------------------------

extern "C" void kernel_launch(void* const* d_in, const int* in_sizes, int n_in,
                              void* d_out, int out_size, void* d_ws, size_t ws_size,
                              hipStream_t stream) {
  const float* x    = (const float*)d_in[0];
  const float* c    = (const float*)d_in[1];
  const float* bias = (const float*)d_in[2];
  float* out = (float*)d_out;

  const size_t xb_elems = (size_t)B_DIM * IN_DIM;
  const size_t rb_elems = (size_t)OUT_DIM * IN_DIM;
  if (ws_size < (xb_elems + rb_elems) * sizeof(unsigned short)) return;

  unsigned short* xb = (unsigned short*)d_ws;
  unsigned short* rb = xb + xb_elems;

  cvt_fused_kernel<<<XCHUNKS + RCHUNKS, 256, 0, stream>>>(x, c, xb, rb);

  const int grid = (B_DIM / 256) * (OUT_DIM / 256);  // 32*16 = 512
  gemm_kernel<<<grid, 512, 0, stream>>>(xb, rb, bias, out);
}

// Round 9
// 189.760 us; speedup vs baseline: 1.5089x; 1.5089x over previous
//
#include <hip/hip_runtime.h>
#include <hip/hip_bf16.h>
#include <stdint.h>

// CirculantLinear == dense GEMM: y[b,o] = sum_n x[b,n]*rows[o,n] + bias[o]
// where rows[o,n] = c[o, (4096-n) & 4095].
// M=8192, N=4096, K=4096. fp32 in/out.
// R3-R8: bf16 MFMA, 256x256/BK64/8-wave; four schedule variants all land
//        242-253us (LDS floor ~2048cy + MFMA floor ~2483cy per K-tile,
//        imperfectly overlapped). Schedule exhausted.
// R9: INT8 path. Per-row symmetric quant (scale=rowmax/127, rint), i8 MFMA
//     16x16x64 (2x K/inst), khalf still [256 rows][64 B] -> staging/swizzle/
//     vmcnt machinery identical to R5; both floors halve. Epilogue rescale
//     acc_i32 * sx[row]*sc[col] + bias.

#define B_DIM  8192
#define OUT_DIM 4096
#define IN_DIM  4096

typedef __attribute__((ext_vector_type(4))) int i32x4;
typedef __attribute__((ext_vector_type(4))) float f32x4;

// ---- fused quantization kernel ------------------------------------------
// One block (256 thr) per row. x rows: blocks [0, B_DIM); c rows (with the
// circulant reverse-roll) : blocks [B_DIM, B_DIM+OUT_DIM).

__global__ void quant_fused_kernel(const float* __restrict__ x,
                                   const float* __restrict__ c,
                                   int8_t* __restrict__ xq,
                                   int8_t* __restrict__ cq,
                                   float* __restrict__ sx,
                                   float* __restrict__ sc) {
  const int row = blockIdx.x;
  const int t = threadIdx.x;
  __shared__ float sm[4];
  float vals[16];

  if (row < B_DIM) {
    const float4* src = (const float4*)(x + (size_t)row * IN_DIM + t * 16);
#pragma unroll
    for (int j = 0; j < 4; ++j) {
      float4 v = src[j];
      vals[4 * j + 0] = v.x; vals[4 * j + 1] = v.y;
      vals[4 * j + 2] = v.z; vals[4 * j + 3] = v.w;
    }
  } else {
    const float* crow = c + (size_t)(row - B_DIM) * IN_DIM;
#pragma unroll
    for (int j = 0; j < 16; ++j) {
      int n = t * 16 + j;
      int s = (IN_DIM - n) & (IN_DIM - 1);
      vals[j] = crow[s];
    }
  }

  float m = 0.f;
#pragma unroll
  for (int j = 0; j < 16; ++j) m = fmaxf(m, fabsf(vals[j]));
#pragma unroll
  for (int k = 32; k; k >>= 1) m = fmaxf(m, __shfl_xor(m, k));
  if ((t & 63) == 0) sm[t >> 6] = m;
  __syncthreads();
  m = fmaxf(fmaxf(sm[0], sm[1]), fmaxf(sm[2], sm[3]));

  const float inv = m > 0.f ? 127.0f / m : 0.f;
  const float scale = m * (1.0f / 127.0f);

  int4 packed;
  int* pw = (int*)&packed;
#pragma unroll
  for (int g = 0; g < 4; ++g) {
    int wbits = 0;
#pragma unroll
    for (int j = 0; j < 4; ++j) {
      float q = rintf(vals[g * 4 + j] * inv);
      q = fminf(fmaxf(q, -127.f), 127.f);
      wbits |= (((int)q) & 0xff) << (8 * j);
    }
    pw[g] = wbits;
  }

  if (row < B_DIM) {
    *(int4*)(xq + (size_t)row * IN_DIM + t * 16) = packed;
    if (t == 0) sx[row] = scale;
  } else {
    *(int4*)(cq + (size_t)(row - B_DIM) * IN_DIM + t * 16) = packed;
    if (t == 0) sc[row - B_DIM] = scale;
  }
}

// ---- GEMM ---------------------------------------------------------------

__device__ __forceinline__ void async_copy16(const void* g, void* l) {
  __builtin_amdgcn_global_load_lds(
      (const __attribute__((address_space(1))) void*)g,
      (__attribute__((address_space(3))) void*)l, 16, 0, 0);
}

#define SMEM_BUF 65536
// Per buffer: [A kh0 16K][A kh1 16K][B kh0 16K][B kh1 16K]; khalf = row-major
// [256 rows][64 B] (= 64 i8 k-elems), 4 x 16B chunks/row, chunk-XOR swizzle
// phys_chunk = logical ^ ((row>>1)&3) (measured 0 conflicts). Stage side
// applies the inverse via the per-lane GLOBAL address (LDS dest linear).
// One K-tile = 128 i8 k-elems (2 khalves); NT = 32.

template<int BUF, int KK, int MH, int SMAT, int SBUF, int SKK, int SOFF, int VM>
__device__ __forceinline__ void phase(char* smem, int aRd, int bRd, int w,
                                      const int8_t* sA, const int8_t* sB,
                                      i32x4* bF, i32x4* aF,
                                      i32x4 (*acc)[4]) {
  const char* base = smem + BUF * SMEM_BUF + KK * 16384;
  if (MH == 0) {
#pragma unroll
    for (int ni = 0; ni < 4; ++ni)
      bF[ni] = *(const i32x4*)(base + 32768 + bRd + ni * 1024);
#pragma unroll
    for (int mi = 0; mi < 4; ++mi)
      aF[mi] = *(const i32x4*)(base + aRd + mi * 1024);
  } else {
#pragma unroll
    for (int mi = 0; mi < 4; ++mi)
      aF[mi] = *(const i32x4*)(base + aRd + (4 + mi) * 1024);
  }
  if (SMAT >= 0) {
    const int8_t* src = (SMAT ? sB : sA) + SOFF;
    char* dst = smem + SBUF * SMEM_BUF + SMAT * 32768 + SKK * 16384 + w * 1024;
    async_copy16(src, dst);                        // rows 0..127 of khalf
    async_copy16(src + 128 * IN_DIM, dst + 8192);  // rows 128..255
  }
  __builtin_amdgcn_s_barrier();
  __builtin_amdgcn_s_setprio(1);
#pragma unroll
  for (int i = 0; i < 4; ++i)
#pragma unroll
    for (int ni = 0; ni < 4; ++ni)
      acc[MH * 4 + i][ni] = __builtin_amdgcn_mfma_i32_16x16x64_i8(
          aF[i], bF[ni], acc[MH * 4 + i][ni], 0, 0, 0);
  __builtin_amdgcn_s_setprio(0);
  if (VM == 4) asm volatile("s_waitcnt vmcnt(4)" ::: "memory");
  if (VM == 0) asm volatile("s_waitcnt vmcnt(0)" ::: "memory");
  __builtin_amdgcn_s_barrier();
}

__global__ __launch_bounds__(512, 2) void gemm_kernel(
    const int8_t* __restrict__ xq,   // [8192][4096] i8
    const int8_t* __restrict__ cq,   // [4096][4096] i8 (circulant rows)
    const float* __restrict__ sx,    // [8192] row scales of x
    const float* __restrict__ sc,    // [4096] row scales of c-rows
    const float* __restrict__ bias,  // [4096]
    float* __restrict__ out) {       // [8192][4096] fp32
  __shared__ __align__(16) char smem[2 * SMEM_BUF];  // 128 KiB

  const int tid = threadIdx.x;
  const int w = tid >> 6, l = tid & 63;
  const int wr = w >> 2, wc = w & 3;       // 2 x 4 wave grid, wave owns 128x64

  // bijective XCD swizzle: 512 blocks = 8 XCDs x 64
  const int orig = blockIdx.x;
  const int wg = (orig & 7) * 64 + (orig >> 3);
  const int bm = (wg >> 4) * 256;
  const int bn = (wg & 15) * 256;

  // staging: phys row r = 16w + (l>>2) (+128 2nd copy); phys chunk = l&3;
  // stored logical chunk = (l&3) ^ ((l>>3)&3) -> pre-swizzled global col.
  // chunk = 16 i8 elements now.
  const int sgr = w * 16 + (l >> 2);
  const int sgc = ((l & 3) ^ ((l >> 3) & 3)) << 4;
  const int8_t* sA = xq + (size_t)(bm + sgr) * IN_DIM + sgc;
  const int8_t* sB = cq + (size_t)(bn + sgr) * IN_DIM + sgc;

  // frag reads: row = 16-aligned base + (l&15), logical chunk (l>>4)
  //   -> phys chunk = (l>>4) ^ ((l>>1)&3)   (byte offsets unchanged)
  const int swz = ((l >> 4) ^ ((l >> 1) & 3)) << 4;
  const int aRd = (wr * 128 + (l & 15)) * 64 + swz;
  const int bRd = (wc * 64 + (l & 15)) * 64 + swz;

  i32x4 acc[8][4];
#pragma unroll
  for (int i = 0; i < 8; ++i)
#pragma unroll
    for (int j = 0; j < 4; ++j) acc[i][j] = (i32x4){0, 0, 0, 0};
  i32x4 aF[4], bF[4];

  // ---- prologue: stage K-tile 0 into buf0 (A-kh0, B-kh0, A-kh1, B-kh1)
  {
    async_copy16(sA,                smem + 0 + w * 1024);
    async_copy16(sA + 128 * IN_DIM, smem + 0 + 8192 + w * 1024);
    async_copy16(sB,                smem + 32768 + w * 1024);
    async_copy16(sB + 128 * IN_DIM, smem + 32768 + 8192 + w * 1024);
    async_copy16(sA + 64,                smem + 16384 + w * 1024);
    async_copy16(sA + 64 + 128 * IN_DIM, smem + 16384 + 8192 + w * 1024);
    async_copy16(sB + 64,                smem + 32768 + 16384 + w * 1024);
    async_copy16(sB + 64 + 128 * IN_DIM, smem + 32768 + 16384 + 8192 + w * 1024);
  }
  sA += 128; sB += 128;   // -> K-tile 1 (first staged in loop)
  asm volatile("s_waitcnt vmcnt(4)" ::: "memory");  // kh0 A+B landed
  __builtin_amdgcn_s_barrier();

  // ---- main loop: 2 K-tiles per iteration, kt = 0..29 (15 iters)
  for (int it = 0; it < 15; ++it) {
    // kt even: compute buf0, stage kt+1 -> buf1
    phase<0,0,0,  0,1,0,   0, -1>(smem, aRd, bRd, w, sA, sB, bF, aF, acc);
    phase<0,0,1,  1,1,0,   0,  4>(smem, aRd, bRd, w, sA, sB, bF, aF, acc);
    phase<0,1,0,  0,1,1,  64, -1>(smem, aRd, bRd, w, sA, sB, bF, aF, acc);
    phase<0,1,1,  1,1,1,  64,  4>(smem, aRd, bRd, w, sA, sB, bF, aF, acc);
    // kt odd: compute buf1, stage kt+2 -> buf0
    phase<1,0,0,  0,0,0, 128, -1>(smem, aRd, bRd, w, sA, sB, bF, aF, acc);
    phase<1,0,1,  1,0,0, 128,  4>(smem, aRd, bRd, w, sA, sB, bF, aF, acc);
    phase<1,1,0,  0,0,1, 192, -1>(smem, aRd, bRd, w, sA, sB, bF, aF, acc);
    phase<1,1,1,  1,0,1, 192,  4>(smem, aRd, bRd, w, sA, sB, bF, aF, acc);
    sA += 256; sB += 256;
  }
  // kt=30: compute buf0, stage kt31 -> buf1
  phase<0,0,0,  0,1,0,   0, -1>(smem, aRd, bRd, w, sA, sB, bF, aF, acc);
  phase<0,0,1,  1,1,0,   0,  4>(smem, aRd, bRd, w, sA, sB, bF, aF, acc);
  phase<0,1,0,  0,1,1,  64, -1>(smem, aRd, bRd, w, sA, sB, bF, aF, acc);
  phase<0,1,1,  1,1,1,  64,  4>(smem, aRd, bRd, w, sA, sB, bF, aF, acc);
  // kt=31: compute buf1, no staging; drain kh1 before its phase-3/4 reads
  phase<1,0,0, -1,0,0,   0, -1>(smem, aRd, bRd, w, sA, sB, bF, aF, acc);
  phase<1,0,1, -1,0,0,   0,  0>(smem, aRd, bRd, w, sA, sB, bF, aF, acc);
  phase<1,1,0, -1,0,0,   0, -1>(smem, aRd, bRd, w, sA, sB, bF, aF, acc);
  phase<1,1,1, -1,0,0,   0, -1>(smem, aRd, bRd, w, sA, sB, bF, aF, acc);

  // ---- epilogue: C/D layout col=lane&15, row=(lane>>4)*4+reg
  // (dtype-independent on gfx950; i8 cell verified m121)
#pragma unroll
  for (int mi = 0; mi < 8; ++mi) {
    const int row = bm + wr * 128 + mi * 16 + (l >> 4) * 4;
    const float4 sx4 = *(const float4*)(sx + row);   // rows row..row+3
#pragma unroll
    for (int ni = 0; ni < 4; ++ni) {
      const int col = bn + wc * 64 + ni * 16 + (l & 15);
      const float scv = sc[col];
      const float bv = bias[col];
      float* po = out + (size_t)row * OUT_DIM + col;
      po[0 * (size_t)OUT_DIM] = (float)acc[mi][ni][0] * (sx4.x * scv) + bv;
      po[1 * (size_t)OUT_DIM] = (float)acc[mi][ni][1] * (sx4.y * scv) + bv;
      po[2 * (size_t)OUT_DIM] = (float)acc[mi][ni][2] * (sx4.z * scv) + bv;
      po[3 * (size_t)OUT_DIM] = (float)acc[mi][ni][3] * (sx4.w * scv) + bv;
    }
  }
}

// ---- host ---------------------------------------------------------------

extern "C" void kernel_launch(void* const* d_in, const int* in_sizes, int n_in,
                              void* d_out, int out_size, void* d_ws, size_t ws_size,
                              hipStream_t stream) {
  const float* x    = (const float*)d_in[0];
  const float* c    = (const float*)d_in[1];
  const float* bias = (const float*)d_in[2];
  float* out = (float*)d_out;

  const size_t xq_bytes = (size_t)B_DIM * IN_DIM;     // 33.5 MB
  const size_t cq_bytes = (size_t)OUT_DIM * IN_DIM;   // 16.8 MB
  const size_t need = xq_bytes + cq_bytes + (B_DIM + OUT_DIM) * sizeof(float);
  if (ws_size < need) return;

  int8_t* xq = (int8_t*)d_ws;
  int8_t* cq = xq + xq_bytes;
  float* sx = (float*)(cq + cq_bytes);
  float* sc = sx + B_DIM;

  quant_fused_kernel<<<B_DIM + OUT_DIM, 256, 0, stream>>>(x, c, xq, cq, sx, sc);

  const int grid = (B_DIM / 256) * (OUT_DIM / 256);  // 512
  gemm_kernel<<<grid, 512, 0, stream>>>(xq, cq, sx, sc, bias, out);
}